// Round 1
// baseline (1963.308 us; speedup 1.0000x reference)
//
#include <hip/hip_runtime.h>
#include <hip/hip_fp16.h>

#define BB 1024
#define SS 128
#define FF 64
#define HH 100

__device__ __forceinline__ float sigmf(float x){ return 1.0f/(1.0f+__expf(-x)); }

__device__ __forceinline__ float wsum(float v){
#pragma unroll
  for (int m = 32; m >= 1; m >>= 1) v += __shfl_xor(v, m, 64);
  return v;
}
__device__ __forceinline__ float wmax(float v){
#pragma unroll
  for (int m = 32; m >= 1; m >>= 1) v = fmaxf(v, __shfl_xor(v, m, 64));
  return v;
}

// ---------------- gram: gram[b,i,j] = sum_s x[b,s,i]*x[b,s,j] ----------------
__global__ __launch_bounds__(256) void k_gram(const float* __restrict__ x, float* __restrict__ gram){
  __shared__ __align__(16) float xs[SS*FF];
  int b = blockIdx.x, tid = threadIdx.x;
  const float* xb = x + (size_t)b*SS*FF;
  for (int i = tid; i < SS*FF/4; i += 256)
    ((float4*)xs)[i] = ((const float4*)xb)[i];
  __syncthreads();
  int ti = (tid & 15) * 4, tj = (tid >> 4) * 4;
  float acc[4][4];
#pragma unroll
  for (int a=0;a<4;++a)
#pragma unroll
    for (int c=0;c<4;++c) acc[a][c]=0.f;
  for (int s = 0; s < SS; ++s) {
    const float* row = xs + s*FF;
    float4 av = *(const float4*)(row + ti);
    float4 bv = *(const float4*)(row + tj);
    float aa[4] = {av.x,av.y,av.z,av.w};
    float bb2[4] = {bv.x,bv.y,bv.z,bv.w};
#pragma unroll
    for (int a=0;a<4;++a)
#pragma unroll
      for (int c=0;c<4;++c) acc[a][c] += aa[a]*bb2[c];
  }
  float* g = gram + (size_t)b*4096;
#pragma unroll
  for (int a=0;a<4;++a)
#pragma unroll
    for (int c=0;c<4;++c) g[(ti+a)*64 + tj + c] = acc[a][c];
}

// ------------- conv1(3x3,1->16,SAME)+bias+relu+maxpool2 -> half [B,16,32,32] -------------
__global__ __launch_bounds__(256) void k_conv1pool(const float* __restrict__ gram,
    const float* __restrict__ c1w, const float* __restrict__ c1b, __half* __restrict__ pool1){
  __shared__ float img2[66*66];
  __shared__ float ws1[144];
  __shared__ float bs1[16];
  int tid=threadIdx.x, b=blockIdx.x;
  for (int i=tid;i<66*66;i+=256) img2[i]=0.f;
  if (tid<144) ws1[tid]=c1w[tid];
  if (tid<16) bs1[tid]=c1b[tid];
  __syncthreads();
  const float* gb = gram + (size_t)b*4096;
  for (int i=tid;i<4096;i+=256){ int y=i>>6, xx=i&63; img2[(y+1)*66 + xx+1] = gb[i]; }
  __syncthreads();
  int oc = tid>>4, slot = tid&15;
  float wr[9];
#pragma unroll
  for (int t=0;t<9;++t) wr[t]=ws1[oc*9+t];
  float bo = bs1[oc];
  for (int p=slot;p<1024;p+=16){
    int py=p>>5, px=p&31;
    int y0=py*2, x0=px*2;
    float v[4][4];
#pragma unroll
    for (int wy=0;wy<4;++wy)
#pragma unroll
      for (int wxx=0;wxx<4;++wxx) v[wy][wxx]=img2[(y0+wy)*66 + x0+wxx];
    float s00=bo,s01=bo,s10=bo,s11=bo;
#pragma unroll
    for (int ky=0;ky<3;++ky)
#pragma unroll
      for (int kx=0;kx<3;++kx){
        float w=wr[ky*3+kx];
        s00 += v[ky][kx]*w;   s01 += v[ky][kx+1]*w;
        s10 += v[ky+1][kx]*w; s11 += v[ky+1][kx+1]*w;
      }
    float mx = fmaxf(fmaxf(s00,s01),fmaxf(s10,s11));
    pool1[(size_t)b*16384 + oc*1024 + p] = __float2half(fmaxf(mx,0.f));
  }
}

// ------------- conv2(3x3,16->32,SAME)+bias+relu, spatial mean -> proc [B,32] -------------
__global__ __launch_bounds__(512) void k_conv2mean(const __half* __restrict__ pool1,
    const float* __restrict__ c2w, const float* __restrict__ c2b, float* __restrict__ proc){
  __shared__ __half img[16*32*34];   // x-padded by 1 on each side
  __shared__ float w2s[4608];
  __shared__ float b2s[32];
  __shared__ float red[512];
  int b = blockIdx.x, tid = threadIdx.x;
  for (int i = tid; i < 16*32*32; i += 512) {
    int ic = i >> 10, rem = i & 1023, y = rem >> 5, xx = rem & 31;
    img[(ic*32 + y)*34 + xx + 1] = pool1[(size_t)b*16384 + i];
  }
  for (int i = tid; i < 16*32; i += 512) {
    int ic = i>>5, y = i&31;
    img[(ic*32+y)*34 + 0]  = __float2half(0.f);
    img[(ic*32+y)*34 + 33] = __float2half(0.f);
  }
  for (int i = tid; i < 4608; i += 512) w2s[i] = c2w[i];
  if (tid < 32) b2s[tid] = c2b[tid];
  __syncthreads();
  int oc = tid >> 4, slot = tid & 15;
  const float* wrow = w2s + oc*144;
  float bias = b2s[oc];
  float accsum = 0.f;
  for (int g = 0; g < 16; ++g) {
    int q = slot + (g<<4);       // group 0..255, 4 px each
    int y = q >> 3, x0 = (q & 7) << 2;
    float s0=bias, s1=bias, s2=bias, s3=bias;
    for (int ic = 0; ic < 16; ++ic) {
      const __half* base = img + (ic*32)*34;
      const float* w9 = wrow + ic*9;
#pragma unroll
      for (int ky = 0; ky < 3; ++ky) {
        int yy = y + ky - 1;
        if ((unsigned)yy < 32u) {
          const __half* r = base + yy*34 + x0;
          float v0=__half2float(r[0]), v1=__half2float(r[1]), v2=__half2float(r[2]),
                v3=__half2float(r[3]), v4=__half2float(r[4]), v5=__half2float(r[5]);
          float wa=w9[ky*3+0], wb=w9[ky*3+1], wc=w9[ky*3+2];
          s0 += v0*wa + v1*wb + v2*wc;
          s1 += v1*wa + v2*wb + v3*wc;
          s2 += v2*wa + v3*wb + v4*wc;
          s3 += v3*wa + v4*wb + v5*wc;
        }
      }
    }
    accsum += fmaxf(s0,0.f)+fmaxf(s1,0.f)+fmaxf(s2,0.f)+fmaxf(s3,0.f);
  }
  red[tid] = accsum;
  __syncthreads();
  if (slot == 0) {
    float t = 0.f;
    for (int i=0;i<16;++i) t += red[(oc<<4)+i];
    proc[b*32 + oc] = t * (1.f/1024.f);
  }
}

// ------------- fs = tanh(x@fW1^T+fb1)@fW2^T+fb2, per (b,s) row -------------
__global__ __launch_bounds__(256) void k_fs(const float* __restrict__ x,
    const float* __restrict__ fW1, const float* __restrict__ fb1,
    const float* __restrict__ fW2, const float* __restrict__ fb2,
    float* __restrict__ fs){
  __shared__ float w1t[64*32];   // w1t[k*32+j] = fW1[j*64+k]
  __shared__ float w2t[32*64];   // w2t[k*64+j] = fW2[j*32+k]
  __shared__ float b1s[32], b2s[64];
  __shared__ __align__(16) float xbuf[4][8][64];
  __shared__ float t1buf[4][8][32];
  int tid=threadIdx.x, wv=tid>>6, lane=tid&63;
  for (int i=tid;i<2048;i+=256){ int j=i>>6,k=i&63; w1t[k*32+j]=fW1[i]; }
  for (int i=tid;i<2048;i+=256){ int j=i>>5,k=i&31; w2t[k*64+j]=fW2[i]; }
  if (tid<32) b1s[tid]=fb1[tid];
  if (tid<64) b2s[tid]=fb2[tid];
  __syncthreads();
  size_t Rw = (size_t)blockIdx.x*64 + wv*16;
  int j = lane & 31, half = lane >> 5;
  for (int pass=0; pass<2; ++pass){
    size_t R0 = Rw + pass*8;
    const float4* src = (const float4*)(x + R0*64);
    float4* dst = (float4*)&xbuf[wv][0][0];
    for (int i=lane;i<128;i+=64) dst[i]=src[i];
    __syncthreads();
    {
      float a0=b1s[j],a1=b1s[j],a2=b1s[j],a3=b1s[j];
      const float* xr = &xbuf[wv][half*4][0];
      for (int k=0;k<64;++k){
        float w = w1t[k*32+j];
        a0 += w*xr[k]; a1 += w*xr[64+k]; a2 += w*xr[128+k]; a3 += w*xr[192+k];
      }
      float* t1r = &t1buf[wv][half*4][0];
      t1r[j]=tanhf(a0); t1r[32+j]=tanhf(a1); t1r[64+j]=tanhf(a2); t1r[96+j]=tanhf(a3);
    }
    __syncthreads();
    {
      float f[8];
#pragma unroll
      for (int r=0;r<8;++r) f[r]=b2s[lane];
      for (int k=0;k<32;++k){
        float w = w2t[k*64+lane];
#pragma unroll
        for (int r=0;r<8;++r) f[r] += w*t1buf[wv][r][k];
      }
#pragma unroll
      for (int r=0;r<8;++r) fs[(R0+r)*64 + lane] = f[r];
    }
    __syncthreads();
  }
}

// ------- aw = tanh([fs,proc]@cW1^T+cb1)@cW2^T+cb2; feature_w=softmax(aw); wx=x*fw -------
__global__ __launch_bounds__(256) void k_attnmlp(const float* __restrict__ x,
    const float* __restrict__ fs, const float* __restrict__ proc,
    const float* __restrict__ cW1, const float* __restrict__ cb1,
    const float* __restrict__ cW2, const float* __restrict__ cb2,
    float* __restrict__ fw_out, float* __restrict__ wx){
  __shared__ float c1t[96*64];
  __shared__ float c2t[64*64];
  __shared__ float cb1s[64], cb2s[64];
  __shared__ float cmb[4][4][96];
  __shared__ float h2b[4][4][64];
  int tid = threadIdx.x, wv = tid>>6, lane = tid&63;
  for (int i = tid; i < 6144; i += 256){ int j = i/96, k = i%96; c1t[k*64+j] = cW1[i]; }
  for (int i = tid; i < 4096; i += 256){ int j = i>>6, k = i&63; c2t[k*64+j] = cW2[i]; }
  if (tid < 64) { cb1s[tid] = cb1[tid]; cb2s[tid] = cb2[tid]; }
  __syncthreads();
  size_t Rw = (size_t)blockIdx.x*64 + wv*16;
  for (int pass = 0; pass < 4; ++pass) {
    size_t R0 = Rw + pass*4;
    for (int i = lane; i < 384; i += 64) {
      int r = i/96, k = i%96;
      size_t R = R0 + r;
      cmb[wv][r][k] = (k < 64) ? fs[R*64 + k] : proc[(R>>7)*32 + (k-64)];
    }
    __syncthreads();
    float h0a=cb1s[lane],h1a=cb1s[lane],h2a=cb1s[lane],h3a=cb1s[lane];
    for (int k = 0; k < 96; ++k) {
      float w = c1t[k*64+lane];
      h0a += w*cmb[wv][0][k]; h1a += w*cmb[wv][1][k];
      h2a += w*cmb[wv][2][k]; h3a += w*cmb[wv][3][k];
    }
    h2b[wv][0][lane]=tanhf(h0a); h2b[wv][1][lane]=tanhf(h1a);
    h2b[wv][2][lane]=tanhf(h2a); h2b[wv][3][lane]=tanhf(h3a);
    __syncthreads();
    float a0=cb2s[lane],a1=cb2s[lane],a2=cb2s[lane],a3=cb2s[lane];
    for (int k = 0; k < 64; ++k) {
      float w = c2t[k*64+lane];
      a0 += w*h2b[wv][0][k]; a1 += w*h2b[wv][1][k];
      a2 += w*h2b[wv][2][k]; a3 += w*h2b[wv][3][k];
    }
    float m0=wmax(a0), m1=wmax(a1), m2=wmax(a2), m3=wmax(a3);
    float e0=__expf(a0-m0), e1=__expf(a1-m1), e2=__expf(a2-m2), e3=__expf(a3-m3);
    float s0=wsum(e0), s1=wsum(e1), s2=wsum(e2), s3=wsum(e3);
    float f0v=e0/s0, f1v=e1/s1, f2v=e2/s2, f3v=e3/s3;
    size_t R;
    R=R0+0; fw_out[R*64+lane]=f0v; wx[R*64+lane]=x[R*64+lane]*f0v;
    R=R0+1; fw_out[R*64+lane]=f1v; wx[R*64+lane]=x[R*64+lane]*f1v;
    R=R0+2; fw_out[R*64+lane]=f2v; wx[R*64+lane]=x[R*64+lane]*f2v;
    R=R0+3; fw_out[R*64+lane]=f3v; wx[R*64+lane]=x[R*64+lane]*f3v;
    __syncthreads();
  }
}

// ------------- encoder LSTM: 4 batch rows per block, 128 steps, weights in registers -------------
__global__ __launch_bounds__(512, 2) void k_enc(const float* __restrict__ wx,
    const float* __restrict__ Wih, const float* __restrict__ Whh,
    const float* __restrict__ bih, const float* __restrict__ bhh,
    float* __restrict__ enc){
  __shared__ __align__(16) float xs[2][4][64];
  __shared__ __align__(16) float hs[4][100];
  __shared__ __align__(16) float zs[4][400];
  int tid = threadIdx.x;
  int b0 = blockIdx.x * 4;
  float4 wih4[16]; float4 whh4[25];
  float bj = 0.f;
  if (tid < 400) {
    const float4* wr = (const float4*)(Wih + (size_t)tid*64);
#pragma unroll
    for (int k=0;k<16;++k) wih4[k] = wr[k];
    const float4* hr = (const float4*)(Whh + (size_t)tid*100);
#pragma unroll
    for (int k=0;k<25;++k) whh4[k] = hr[k];
    bj = bih[tid] + bhh[tid];
  }
  float c0v=0.f,c1v=0.f,c2v=0.f,c3v=0.f;
  for (int i = tid; i < 400; i += 512) hs[i/100][i%100] = 0.f;
  for (int i = tid; i < 256; i += 512)
    xs[0][i>>6][i&63] = wx[((size_t)(b0 + (i>>6))*SS + 0)*FF + (i&63)];
  __syncthreads();
  for (int t = 0; t < SS; ++t) {
    int cur = t & 1;
    if (tid >= 400) {
      if (t < SS-1) {
        for (int i = tid-400; i < 256; i += 112)
          xs[cur^1][i>>6][i&63] = wx[((size_t)(b0 + (i>>6))*SS + t+1)*FF + (i&63)];
      }
    } else {
      float a0=bj,a1=bj,a2=bj,a3=bj;
#pragma unroll
      for (int k=0;k<16;++k){
        float4 w = wih4[k];
        float4 v0 = *(const float4*)&xs[cur][0][k*4];
        float4 v1 = *(const float4*)&xs[cur][1][k*4];
        float4 v2 = *(const float4*)&xs[cur][2][k*4];
        float4 v3 = *(const float4*)&xs[cur][3][k*4];
        a0 += w.x*v0.x + w.y*v0.y + w.z*v0.z + w.w*v0.w;
        a1 += w.x*v1.x + w.y*v1.y + w.z*v1.z + w.w*v1.w;
        a2 += w.x*v2.x + w.y*v2.y + w.z*v2.z + w.w*v2.w;
        a3 += w.x*v3.x + w.y*v3.y + w.z*v3.z + w.w*v3.w;
      }
#pragma unroll
      for (int k=0;k<25;++k){
        float4 w = whh4[k];
        float4 v0 = *(const float4*)&hs[0][k*4];
        float4 v1 = *(const float4*)&hs[1][k*4];
        float4 v2 = *(const float4*)&hs[2][k*4];
        float4 v3 = *(const float4*)&hs[3][k*4];
        a0 += w.x*v0.x + w.y*v0.y + w.z*v0.z + w.w*v0.w;
        a1 += w.x*v1.x + w.y*v1.y + w.z*v1.z + w.w*v1.w;
        a2 += w.x*v2.x + w.y*v2.y + w.z*v2.z + w.w*v2.w;
        a3 += w.x*v3.x + w.y*v3.y + w.z*v3.z + w.w*v3.w;
      }
      zs[0][tid]=a0; zs[1][tid]=a1; zs[2][tid]=a2; zs[3][tid]=a3;
    }
    __syncthreads();
    if (tid < 100) {
      {
        float iv=zs[0][tid], fv=zs[0][tid+100], gv=zs[0][tid+200], ov=zs[0][tid+300];
        float cn = sigmf(fv)*c0v + sigmf(iv)*tanhf(gv);
        float hn = sigmf(ov)*tanhf(cn);
        c0v = cn; hs[0][tid] = hn;
        enc[((size_t)(b0+0)*SS + t)*HH + tid] = hn;
      }
      {
        float iv=zs[1][tid], fv=zs[1][tid+100], gv=zs[1][tid+200], ov=zs[1][tid+300];
        float cn = sigmf(fv)*c1v + sigmf(iv)*tanhf(gv);
        float hn = sigmf(ov)*tanhf(cn);
        c1v = cn; hs[1][tid] = hn;
        enc[((size_t)(b0+1)*SS + t)*HH + tid] = hn;
      }
      {
        float iv=zs[2][tid], fv=zs[2][tid+100], gv=zs[2][tid+200], ov=zs[2][tid+300];
        float cn = sigmf(fv)*c2v + sigmf(iv)*tanhf(gv);
        float hn = sigmf(ov)*tanhf(cn);
        c2v = cn; hs[2][tid] = hn;
        enc[((size_t)(b0+2)*SS + t)*HH + tid] = hn;
      }
      {
        float iv=zs[3][tid], fv=zs[3][tid+100], gv=zs[3][tid+200], ov=zs[3][tid+300];
        float cn = sigmf(fv)*c3v + sigmf(iv)*tanhf(gv);
        float hn = sigmf(ov)*tanhf(cn);
        c3v = cn; hs[3][tid] = hn;
        enc[((size_t)(b0+3)*SS + t)*HH + tid] = hn;
      }
    }
    __syncthreads();
  }
}

// ------- ts/time_w softmax over S, ctx, bott, dh0, dc0, decpre; one block per batch -------
__global__ __launch_bounds__(256) void k_attn(const float* __restrict__ enc,
    const float* __restrict__ aW1, const float* __restrict__ ab1,
    const float* __restrict__ aW2, const float* __restrict__ ab2,
    const float* __restrict__ bW, const float* __restrict__ bb_,
    const float* __restrict__ h0W, const float* __restrict__ h0b,
    const float* __restrict__ c0W, const float* __restrict__ c0b,
    const float* __restrict__ dWih, const float* __restrict__ dbih, const float* __restrict__ dbhh,
    float* __restrict__ tw_out, float* __restrict__ dh0, float* __restrict__ dc0,
    float* __restrict__ decpre){
  __shared__ float a1t[100*64];
  __shared__ float a2s[64], ab1s[64];
  __shared__ float tsb[SS];
  __shared__ float ctxb[HH];
  __shared__ float bottb[32];
  __shared__ float red[8];
  int tid = threadIdx.x, wv = tid>>6, lane = tid&63;
  int b = blockIdx.x;
  const float* encb = enc + (size_t)b*SS*HH;
  for (int i=tid;i<6400;i+=256){ int jj=i/100,k=i%100; a1t[k*64+jj]=aW1[i]; }
  if (tid<64){ a2s[tid]=aW2[tid]; ab1s[tid]=ab1[tid]; }
  __syncthreads();
  float ab2v = ab2[0];
  for (int si=0; si<32; ++si){
    int s = wv*32+si;
    const float4* er = (const float4*)(encb + s*HH);
    float a = ab1s[lane];
#pragma unroll
    for (int kc=0;kc<25;++kc){
      float4 e = er[kc];
      a += e.x*a1t[(kc*4+0)*64+lane] + e.y*a1t[(kc*4+1)*64+lane]
         + e.z*a1t[(kc*4+2)*64+lane] + e.w*a1t[(kc*4+3)*64+lane];
    }
    float contrib = a2s[lane]*tanhf(a);
    float t = wsum(contrib);
    if (lane==0) tsb[s] = t + ab2v;
  }
  __syncthreads();
  float tv = (tid < SS) ? tsb[tid] : -1e30f;
  float m = wmax(tv);
  if (lane==0) red[wv]=m;
  __syncthreads();
  m = fmaxf(fmaxf(red[0],red[1]), fmaxf(red[2],red[3]));
  float e = (tid < SS) ? __expf(tv - m) : 0.f;
  float sm = wsum(e);
  if (lane==0) red[4+wv]=sm;
  __syncthreads();
  float denom = red[4]+red[5]+red[6]+red[7];
  if (tid < SS){
    float twv = e/denom;
    tw_out[(size_t)b*SS + tid] = twv;
    tsb[tid] = twv;
  }
  __syncthreads();
  if (tid < HH){
    float a = 0.f;
    for (int s=0;s<SS;++s) a += tsb[s]*encb[s*HH + tid];
    ctxb[tid]=a;
  }
  __syncthreads();
  if (tid < 32){
    float a = bb_[tid];
    const float* wr = bW + tid*HH;
    for (int k=0;k<HH;++k) a += wr[k]*ctxb[k];
    bottb[tid]=a;
  }
  __syncthreads();
  if (tid < HH){
    float a = h0b[tid];
    const float* wr = h0W + tid*32;
#pragma unroll
    for (int k=0;k<32;++k) a += wr[k]*bottb[k];
    dh0[(size_t)b*HH + tid] = a;
  } else if (tid < 200){
    int jj = tid-100;
    float a = c0b[jj];
    const float* wr = c0W + jj*32;
#pragma unroll
    for (int k=0;k<32;++k) a += wr[k]*bottb[k];
    dc0[(size_t)b*HH + jj] = a;
  }
  {
    int jj = tid;
    float a = dbih[jj]+dbhh[jj];
    const float* wr = dWih + jj*32;
#pragma unroll
    for (int k=0;k<32;++k) a += wr[k]*bottb[k];
    decpre[(size_t)b*400 + jj] = a;
    jj = tid + 256;
    if (jj < 400){
      float a2v = dbih[jj]+dbhh[jj];
      const float* wr2 = dWih + jj*32;
#pragma unroll
      for (int k=0;k<32;++k) a2v += wr2[k]*bottb[k];
      decpre[(size_t)b*400 + jj] = a2v;
    }
  }
}

// ------------- decoder LSTM: constant input transform precomputed per batch row -------------
__global__ __launch_bounds__(512, 2) void k_dec(const float* __restrict__ decpre,
    const float* __restrict__ Whh,
    const float* __restrict__ dh0, const float* __restrict__ dc0,
    float* __restrict__ dec){
  __shared__ __align__(16) float hs[4][100];
  __shared__ __align__(16) float zs[4][400];
  int tid = threadIdx.x;
  int b0 = blockIdx.x*4;
  float4 whh4[25];
  float pre0=0.f,pre1=0.f,pre2=0.f,pre3=0.f;
  if (tid < 400){
    const float4* hr = (const float4*)(Whh + (size_t)tid*100);
#pragma unroll
    for (int k=0;k<25;++k) whh4[k]=hr[k];
    pre0 = decpre[(size_t)(b0+0)*400 + tid];
    pre1 = decpre[(size_t)(b0+1)*400 + tid];
    pre2 = decpre[(size_t)(b0+2)*400 + tid];
    pre3 = decpre[(size_t)(b0+3)*400 + tid];
  }
  float c0v=0.f,c1v=0.f,c2v=0.f,c3v=0.f;
  if (tid < 100){
    hs[0][tid]=dh0[(size_t)(b0+0)*100+tid];
    hs[1][tid]=dh0[(size_t)(b0+1)*100+tid];
    hs[2][tid]=dh0[(size_t)(b0+2)*100+tid];
    hs[3][tid]=dh0[(size_t)(b0+3)*100+tid];
    c0v=dc0[(size_t)(b0+0)*100+tid];
    c1v=dc0[(size_t)(b0+1)*100+tid];
    c2v=dc0[(size_t)(b0+2)*100+tid];
    c3v=dc0[(size_t)(b0+3)*100+tid];
  }
  __syncthreads();
  for (int t=0;t<SS;++t){
    if (tid < 400){
      float a0=pre0,a1=pre1,a2=pre2,a3=pre3;
#pragma unroll
      for (int k=0;k<25;++k){
        float4 w = whh4[k];
        float4 v0 = *(const float4*)&hs[0][k*4];
        float4 v1 = *(const float4*)&hs[1][k*4];
        float4 v2 = *(const float4*)&hs[2][k*4];
        float4 v3 = *(const float4*)&hs[3][k*4];
        a0 += w.x*v0.x + w.y*v0.y + w.z*v0.z + w.w*v0.w;
        a1 += w.x*v1.x + w.y*v1.y + w.z*v1.z + w.w*v1.w;
        a2 += w.x*v2.x + w.y*v2.y + w.z*v2.z + w.w*v2.w;
        a3 += w.x*v3.x + w.y*v3.y + w.z*v3.z + w.w*v3.w;
      }
      zs[0][tid]=a0; zs[1][tid]=a1; zs[2][tid]=a2; zs[3][tid]=a3;
    }
    __syncthreads();
    if (tid < 100){
      {
        float iv=zs[0][tid], fv=zs[0][tid+100], gv=zs[0][tid+200], ov=zs[0][tid+300];
        float cn = sigmf(fv)*c0v + sigmf(iv)*tanhf(gv);
        float hn = sigmf(ov)*tanhf(cn);
        c0v = cn; hs[0][tid] = hn;
        dec[((size_t)(b0+0)*SS + t)*HH + tid] = hn;
      }
      {
        float iv=zs[1][tid], fv=zs[1][tid+100], gv=zs[1][tid+200], ov=zs[1][tid+300];
        float cn = sigmf(fv)*c1v + sigmf(iv)*tanhf(gv);
        float hn = sigmf(ov)*tanhf(cn);
        c1v = cn; hs[1][tid] = hn;
        dec[((size_t)(b0+1)*SS + t)*HH + tid] = hn;
      }
      {
        float iv=zs[2][tid], fv=zs[2][tid+100], gv=zs[2][tid+200], ov=zs[2][tid+300];
        float cn = sigmf(fv)*c2v + sigmf(iv)*tanhf(gv);
        float hn = sigmf(ov)*tanhf(cn);
        c2v = cn; hs[2][tid] = hn;
        dec[((size_t)(b0+2)*SS + t)*HH + tid] = hn;
      }
      {
        float iv=zs[3][tid], fv=zs[3][tid+100], gv=zs[3][tid+200], ov=zs[3][tid+300];
        float cn = sigmf(fv)*c3v + sigmf(iv)*tanhf(gv);
        float hn = sigmf(ov)*tanhf(cn);
        c3v = cn; hs[3][tid] = hn;
        dec[((size_t)(b0+3)*SS + t)*HH + tid] = hn;
      }
    }
    __syncthreads();
  }
}

// ------------- out = dec @ oW^T + ob -------------
__global__ __launch_bounds__(256) void k_out(const float* __restrict__ dec,
    const float* __restrict__ oW, const float* __restrict__ ob, float* __restrict__ out0){
  __shared__ float oWt[100*64];
  __shared__ float dsr[64*100];
  int tid=threadIdx.x;
  size_t R0 = (size_t)blockIdx.x*64;
  for (int i=tid;i<6400;i+=256){ int j=i/100,k=i%100; oWt[k*64+j]=oW[i]; }
  for (int i=tid;i<6400;i+=256) dsr[i]=dec[R0*100 + i];
  __syncthreads();
  int j = tid&63, rb = tid>>6;
  float acc[16];
#pragma unroll
  for (int i=0;i<16;++i) acc[i]=0.f;
  for (int k=0;k<100;++k){
    float w = oWt[k*64+j];
#pragma unroll
    for (int i=0;i<16;++i) acc[i] += w*dsr[(rb + i*4)*100 + k];
  }
  float obv = ob[j];
#pragma unroll
  for (int i=0;i<16;++i) out0[(R0 + rb + i*4)*64 + j] = acc[i] + obv;
}

extern "C" void kernel_launch(void* const* d_in, const int* in_sizes, int n_in,
                              void* d_out, int out_size, void* d_ws, size_t ws_size,
                              hipStream_t stream) {
  const float* x    = (const float*)d_in[0];
  const float* c1w  = (const float*)d_in[1];
  const float* c1b  = (const float*)d_in[2];
  const float* c2w  = (const float*)d_in[3];
  const float* c2b  = (const float*)d_in[4];
  const float* fW1  = (const float*)d_in[5];
  const float* fb1  = (const float*)d_in[6];
  const float* fW2  = (const float*)d_in[7];
  const float* fb2  = (const float*)d_in[8];
  const float* cW1  = (const float*)d_in[9];
  const float* cb1  = (const float*)d_in[10];
  const float* cW2  = (const float*)d_in[11];
  const float* cb2  = (const float*)d_in[12];
  const float* eWih = (const float*)d_in[13];
  const float* eWhh = (const float*)d_in[14];
  const float* ebih = (const float*)d_in[15];
  const float* ebhh = (const float*)d_in[16];
  const float* aW1  = (const float*)d_in[17];
  const float* ab1  = (const float*)d_in[18];
  const float* aW2  = (const float*)d_in[19];
  const float* ab2  = (const float*)d_in[20];
  const float* bW   = (const float*)d_in[21];
  const float* bb   = (const float*)d_in[22];
  const float* h0W  = (const float*)d_in[23];
  const float* h0b  = (const float*)d_in[24];
  const float* c0W  = (const float*)d_in[25];
  const float* c0b  = (const float*)d_in[26];
  const float* dWih = (const float*)d_in[27];
  const float* dWhh = (const float*)d_in[28];
  const float* dbih = (const float*)d_in[29];
  const float* dbhh = (const float*)d_in[30];
  const float* oW   = (const float*)d_in[31];
  const float* ob   = (const float*)d_in[32];

  float* out0   = (float*)d_out;
  float* out_tw = out0 + (size_t)BB*SS*FF;
  float* out_fw = out_tw + (size_t)BB*SS;

  char* ws = (char*)d_ws;
  float*  gram   = (float*) (ws + 0);           // 16.78 MB
  __half* pool1  = (__half*)(ws + 16777216);    // 33.55 MB
  float*  proc   = (float*) (ws + 50331648);    // 0.13 MB
  float*  fsbuf  = (float*) (ws + 50462720);    // 33.55 MB
  float*  wx     = (float*) (ws + 84017152);    // 33.55 MB
  float*  enc    = (float*) (ws + 117571584);   // 52.43 MB
  float*  dh0    = (float*) (ws + 170000384);   // 0.41 MB
  float*  dc0    = (float*) (ws + 170409984);   // 0.41 MB
  float*  decpre = (float*) (ws + 170819584);   // 1.64 MB
  float*  dec    = (float*) (ws + 172457984);   // 52.43 MB  (end ~224.9 MB)

  k_gram<<<BB, 256, 0, stream>>>(x, gram);
  k_conv1pool<<<BB, 256, 0, stream>>>(gram, c1w, c1b, pool1);
  k_conv2mean<<<BB, 512, 0, stream>>>(pool1, c2w, c2b, proc);
  k_fs<<<2048, 256, 0, stream>>>(x, fW1, fb1, fW2, fb2, fsbuf);
  k_attnmlp<<<2048, 256, 0, stream>>>(x, fsbuf, proc, cW1, cb1, cW2, cb2, out_fw, wx);
  k_enc<<<256, 512, 0, stream>>>(wx, eWih, eWhh, ebih, ebhh, enc);
  k_attn<<<BB, 256, 0, stream>>>(enc, aW1, ab1, aW2, ab2, bW, bb, h0W, h0b, c0W, c0b,
                                 dWih, dbih, dbhh, out_tw, dh0, dc0, decpre);
  k_dec<<<256, 512, 0, stream>>>(decpre, dWhh, dh0, dc0, dec);
  k_out<<<2048, 256, 0, stream>>>(dec, oW, ob, out0);
}

// Round 3
// 1402.378 us; speedup vs baseline: 1.4000x; 1.4000x over previous
//
#include <hip/hip_runtime.h>
#include <hip/hip_fp16.h>

#define BB 1024
#define SS 128
#define FF 64
#define HH 100

typedef _Float16 h8 __attribute__((ext_vector_type(8)));
typedef float f4v __attribute__((ext_vector_type(4)));

__device__ __forceinline__ float sigmf(float x){ return 1.0f/(1.0f+__expf(-x)); }

__device__ __forceinline__ float wsum(float v){
#pragma unroll
  for (int m = 32; m >= 1; m >>= 1) v += __shfl_xor(v, m, 64);
  return v;
}
__device__ __forceinline__ float wmax(float v){
#pragma unroll
  for (int m = 32; m >= 1; m >>= 1) v = fmaxf(v, __shfl_xor(v, m, 64));
  return v;
}

// ---------------- gram: gram[b,i,j] = sum_s x[b,s,i]*x[b,s,j] ----------------
__global__ __launch_bounds__(256) void k_gram(const float* __restrict__ x, float* __restrict__ gram){
  __shared__ __align__(16) float xs[SS*FF];
  int b = blockIdx.x, tid = threadIdx.x;
  const float* xb = x + (size_t)b*SS*FF;
  for (int i = tid; i < SS*FF/4; i += 256)
    ((float4*)xs)[i] = ((const float4*)xb)[i];
  __syncthreads();
  int ti = (tid & 15) * 4, tj = (tid >> 4) * 4;
  float acc[4][4];
#pragma unroll
  for (int a=0;a<4;++a)
#pragma unroll
    for (int c=0;c<4;++c) acc[a][c]=0.f;
  for (int s = 0; s < SS; ++s) {
    const float* row = xs + s*FF;
    float4 av = *(const float4*)(row + ti);
    float4 bv = *(const float4*)(row + tj);
    float aa[4] = {av.x,av.y,av.z,av.w};
    float bb2[4] = {bv.x,bv.y,bv.z,bv.w};
#pragma unroll
    for (int a=0;a<4;++a)
#pragma unroll
      for (int c=0;c<4;++c) acc[a][c] += aa[a]*bb2[c];
  }
  float* g = gram + (size_t)b*4096;
#pragma unroll
  for (int a=0;a<4;++a)
#pragma unroll
    for (int c=0;c<4;++c) g[(ti+a)*64 + tj + c] = acc[a][c];
}

// ------------- conv1(3x3,1->16,SAME)+bias+relu+maxpool2 -> half [B,16,32,32] -------------
__global__ __launch_bounds__(256) void k_conv1pool(const float* __restrict__ gram,
    const float* __restrict__ c1w, const float* __restrict__ c1b, __half* __restrict__ pool1){
  __shared__ float img2[66*66];
  __shared__ float ws1[144];
  __shared__ float bs1[16];
  int tid=threadIdx.x, b=blockIdx.x;
  for (int i=tid;i<66*66;i+=256) img2[i]=0.f;
  if (tid<144) ws1[tid]=c1w[tid];
  if (tid<16) bs1[tid]=c1b[tid];
  __syncthreads();
  const float* gb = gram + (size_t)b*4096;
  for (int i=tid;i<4096;i+=256){ int y=i>>6, xx=i&63; img2[(y+1)*66 + xx+1] = gb[i]; }
  __syncthreads();
  int oc = tid>>4, slot = tid&15;
  float wr[9];
#pragma unroll
  for (int t=0;t<9;++t) wr[t]=ws1[oc*9+t];
  float bo = bs1[oc];
  for (int p=slot;p<1024;p+=16){
    int py=p>>5, px=p&31;
    int y0=py*2, x0=px*2;
    float v[4][4];
#pragma unroll
    for (int wy=0;wy<4;++wy)
#pragma unroll
      for (int wxx=0;wxx<4;++wxx) v[wy][wxx]=img2[(y0+wy)*66 + x0+wxx];
    float s00=bo,s01=bo,s10=bo,s11=bo;
#pragma unroll
    for (int ky=0;ky<3;++ky)
#pragma unroll
      for (int kx=0;kx<3;++kx){
        float w=wr[ky*3+kx];
        s00 += v[ky][kx]*w;   s01 += v[ky][kx+1]*w;
        s10 += v[ky+1][kx]*w; s11 += v[ky+1][kx+1]*w;
      }
    float mx = fmaxf(fmaxf(s00,s01),fmaxf(s10,s11));
    pool1[(size_t)b*16384 + oc*1024 + p] = __float2half(fmaxf(mx,0.f));
  }
}

// ------------- conv2(3x3,16->32,SAME)+bias+relu, spatial mean -> proc [B,32] -------------
__global__ __launch_bounds__(512) void k_conv2mean(const __half* __restrict__ pool1,
    const float* __restrict__ c2w, const float* __restrict__ c2b, float* __restrict__ proc){
  __shared__ __half img[16*32*34];   // x-padded by 1 on each side
  __shared__ float w2s[4608];
  __shared__ float b2s[32];
  __shared__ float red[512];
  int b = blockIdx.x, tid = threadIdx.x;
  for (int i = tid; i < 16*32*32; i += 512) {
    int ic = i >> 10, rem = i & 1023, y = rem >> 5, xx = rem & 31;
    img[(ic*32 + y)*34 + xx + 1] = pool1[(size_t)b*16384 + i];
  }
  for (int i = tid; i < 16*32; i += 512) {
    int ic = i>>5, y = i&31;
    img[(ic*32+y)*34 + 0]  = __float2half(0.f);
    img[(ic*32+y)*34 + 33] = __float2half(0.f);
  }
  for (int i = tid; i < 4608; i += 512) w2s[i] = c2w[i];
  if (tid < 32) b2s[tid] = c2b[tid];
  __syncthreads();
  int oc = tid >> 4, slot = tid & 15;
  const float* wrow = w2s + oc*144;
  float bias = b2s[oc];
  float accsum = 0.f;
  for (int g = 0; g < 16; ++g) {
    int q = slot + (g<<4);       // group 0..255, 4 px each
    int y = q >> 3, x0 = (q & 7) << 2;
    float s0=bias, s1=bias, s2=bias, s3=bias;
    for (int ic = 0; ic < 16; ++ic) {
      const __half* base = img + (ic*32)*34;
      const float* w9 = wrow + ic*9;
#pragma unroll
      for (int ky = 0; ky < 3; ++ky) {
        int yy = y + ky - 1;
        if ((unsigned)yy < 32u) {
          const __half* r = base + yy*34 + x0;
          float v0=__half2float(r[0]), v1=__half2float(r[1]), v2=__half2float(r[2]),
                v3=__half2float(r[3]), v4=__half2float(r[4]), v5=__half2float(r[5]);
          float wa=w9[ky*3+0], wb=w9[ky*3+1], wc=w9[ky*3+2];
          s0 += v0*wa + v1*wb + v2*wc;
          s1 += v1*wa + v2*wb + v3*wc;
          s2 += v2*wa + v3*wb + v4*wc;
          s3 += v3*wa + v4*wb + v5*wc;
        }
      }
    }
    accsum += fmaxf(s0,0.f)+fmaxf(s1,0.f)+fmaxf(s2,0.f)+fmaxf(s3,0.f);
  }
  red[tid] = accsum;
  __syncthreads();
  if (slot == 0) {
    float t = 0.f;
    for (int i=0;i<16;++i) t += red[(oc<<4)+i];
    proc[b*32 + oc] = t * (1.f/1024.f);
  }
}

// ------------- fs = tanh(x@fW1^T+fb1)@fW2^T+fb2, per (b,s) row -------------
__global__ __launch_bounds__(256) void k_fs(const float* __restrict__ x,
    const float* __restrict__ fW1, const float* __restrict__ fb1,
    const float* __restrict__ fW2, const float* __restrict__ fb2,
    float* __restrict__ fs){
  __shared__ float w1t[64*32];   // w1t[k*32+j] = fW1[j*64+k]
  __shared__ float w2t[32*64];   // w2t[k*64+j] = fW2[j*32+k]
  __shared__ float b1s[32], b2s[64];
  __shared__ __align__(16) float xbuf[4][8][64];
  __shared__ float t1buf[4][8][32];
  int tid=threadIdx.x, wv=tid>>6, lane=tid&63;
  for (int i=tid;i<2048;i+=256){ int j=i>>6,k=i&63; w1t[k*32+j]=fW1[i]; }
  for (int i=tid;i<2048;i+=256){ int j=i>>5,k=i&31; w2t[k*64+j]=fW2[i]; }
  if (tid<32) b1s[tid]=fb1[tid];
  if (tid<64) b2s[tid]=fb2[tid];
  __syncthreads();
  size_t Rw = (size_t)blockIdx.x*64 + wv*16;
  int j = lane & 31, half = lane >> 5;
  for (int pass=0; pass<2; ++pass){
    size_t R0 = Rw + pass*8;
    const float4* src = (const float4*)(x + R0*64);
    float4* dst = (float4*)&xbuf[wv][0][0];
    for (int i=lane;i<128;i+=64) dst[i]=src[i];
    __syncthreads();
    {
      float a0=b1s[j],a1=b1s[j],a2=b1s[j],a3=b1s[j];
      const float* xr = &xbuf[wv][half*4][0];
      for (int k=0;k<64;++k){
        float w = w1t[k*32+j];
        a0 += w*xr[k]; a1 += w*xr[64+k]; a2 += w*xr[128+k]; a3 += w*xr[192+k];
      }
      float* t1r = &t1buf[wv][half*4][0];
      t1r[j]=tanhf(a0); t1r[32+j]=tanhf(a1); t1r[64+j]=tanhf(a2); t1r[96+j]=tanhf(a3);
    }
    __syncthreads();
    {
      float f[8];
#pragma unroll
      for (int r=0;r<8;++r) f[r]=b2s[lane];
      for (int k=0;k<32;++k){
        float w = w2t[k*64+lane];
#pragma unroll
        for (int r=0;r<8;++r) f[r] += w*t1buf[wv][r][k];
      }
#pragma unroll
      for (int r=0;r<8;++r) fs[(R0+r)*64 + lane] = f[r];
    }
    __syncthreads();
  }
}

// ------- aw = tanh([fs,proc]@cW1^T+cb1)@cW2^T+cb2; feature_w=softmax(aw); wx=x*fw -------
__global__ __launch_bounds__(256) void k_attnmlp(const float* __restrict__ x,
    const float* __restrict__ fs, const float* __restrict__ proc,
    const float* __restrict__ cW1, const float* __restrict__ cb1,
    const float* __restrict__ cW2, const float* __restrict__ cb2,
    float* __restrict__ fw_out, float* __restrict__ wx){
  __shared__ float c1t[96*64];
  __shared__ float c2t[64*64];
  __shared__ float cb1s[64], cb2s[64];
  __shared__ float cmb[4][4][96];
  __shared__ float h2b[4][4][64];
  int tid = threadIdx.x, wv = tid>>6, lane = tid&63;
  for (int i = tid; i < 6144; i += 256){ int j = i/96, k = i%96; c1t[k*64+j] = cW1[i]; }
  for (int i = tid; i < 4096; i += 256){ int j = i>>6, k = i&63; c2t[k*64+j] = cW2[i]; }
  if (tid < 64) { cb1s[tid] = cb1[tid]; cb2s[tid] = cb2[tid]; }
  __syncthreads();
  size_t Rw = (size_t)blockIdx.x*64 + wv*16;
  for (int pass = 0; pass < 4; ++pass) {
    size_t R0 = Rw + pass*4;
    for (int i = lane; i < 384; i += 64) {
      int r = i/96, k = i%96;
      size_t R = R0 + r;
      cmb[wv][r][k] = (k < 64) ? fs[R*64 + k] : proc[(R>>7)*32 + (k-64)];
    }
    __syncthreads();
    float h0a=cb1s[lane],h1a=cb1s[lane],h2a=cb1s[lane],h3a=cb1s[lane];
    for (int k = 0; k < 96; ++k) {
      float w = c1t[k*64+lane];
      h0a += w*cmb[wv][0][k]; h1a += w*cmb[wv][1][k];
      h2a += w*cmb[wv][2][k]; h3a += w*cmb[wv][3][k];
    }
    h2b[wv][0][lane]=tanhf(h0a); h2b[wv][1][lane]=tanhf(h1a);
    h2b[wv][2][lane]=tanhf(h2a); h2b[wv][3][lane]=tanhf(h3a);
    __syncthreads();
    float a0=cb2s[lane],a1=cb2s[lane],a2=cb2s[lane],a3=cb2s[lane];
    for (int k = 0; k < 64; ++k) {
      float w = c2t[k*64+lane];
      a0 += w*h2b[wv][0][k]; a1 += w*h2b[wv][1][k];
      a2 += w*h2b[wv][2][k]; a3 += w*h2b[wv][3][k];
    }
    float m0=wmax(a0), m1=wmax(a1), m2=wmax(a2), m3=wmax(a3);
    float e0=__expf(a0-m0), e1=__expf(a1-m1), e2=__expf(a2-m2), e3=__expf(a3-m3);
    float s0=wsum(e0), s1=wsum(e1), s2=wsum(e2), s3=wsum(e3);
    float f0v=e0/s0, f1v=e1/s1, f2v=e2/s2, f3v=e3/s3;
    size_t R;
    R=R0+0; fw_out[R*64+lane]=f0v; wx[R*64+lane]=x[R*64+lane]*f0v;
    R=R0+1; fw_out[R*64+lane]=f1v; wx[R*64+lane]=x[R*64+lane]*f1v;
    R=R0+2; fw_out[R*64+lane]=f2v; wx[R*64+lane]=x[R*64+lane]*f2v;
    R=R0+3; fw_out[R*64+lane]=f3v; wx[R*64+lane]=x[R*64+lane]*f3v;
    __syncthreads();
  }
}

// ================= MFMA encoder LSTM =================
// 64 blocks x 448 threads (7 waves). Block owns 16 batch rows; wave w owns
// units [16w,16w+16) for all 4 gates (4 N-tiles). Weights live in VGPRs.
// NOTE: BOTH hbuf phases must be zeroed — units 112..127 are owned by no
// wave and are read (against zero weights) every step; stale LDS there was
// the R2 NaN (garbage f16 can be Inf/NaN, and NaN*0 = NaN in MFMA).
__global__ __launch_bounds__(448, 2) void k_enc_mfma(const float* __restrict__ wx,
    const float* __restrict__ Wih, const float* __restrict__ Whh,
    const float* __restrict__ bih, const float* __restrict__ bhh,
    float* __restrict__ enc){
  __shared__ __align__(16) _Float16 hbuf[2][16*128];
  __shared__ __align__(16) _Float16 xst[2][16*64];
  int tid = threadIdx.x;
  int w = tid >> 6, l = tid & 63;
  int lm = l & 15, lq = l >> 4;
  int b0 = blockIdx.x * 16;
  // ---- load B fragments (weights) into registers, f32 -> f16 ----
  h8 bfr[4][6];
  float biasv[4];
  int uu = w*16 + lm;
  bool uvalid = uu < 100;
#pragma unroll
  for (int tt = 0; tt < 4; ++tt) {
    int row = tt*100 + uu;
    biasv[tt] = uvalid ? (bih[row] + bhh[row]) : 0.f;
#pragma unroll
    for (int cc = 0; cc < 6; ++cc) {
      h8 f;
#pragma unroll
      for (int j = 0; j < 8; ++j) {
        int kg = cc*32 + lq*8 + j;
        float v = 0.f;
        if (uvalid) {
          if (kg < 64) v = Wih[(size_t)row*64 + kg];
          else { int kh = kg - 64; if (kh < 100) v = Whh[(size_t)row*100 + kh]; }
        }
        f[j] = (_Float16)v;
      }
      bfr[tt][cc] = f;
    }
  }
  // zero BOTH h buffers and xst[1] (anti-NaN: no stale LDS may reach MFMA)
  for (int i = tid; i < 2*16*128; i += 448) hbuf[0][i] = (_Float16)0.f;
  for (int i = tid; i < 16*64; i += 448) xst[1][i] = (_Float16)0.f;
  // stage x_0 (threads 0..255: one float4 each)
  int sm = tid >> 4, skq = tid & 15;
  __syncthreads();
  if (tid < 256) {
    float4 xv0 = *(const float4*)(wx + ((size_t)(b0+sm)*SS + 0)*FF + skq*4);
    int kb = skq >> 1, j0 = (skq & 1)*4;
    _Float16* dst = &xst[0][sm*64 + ((kb ^ (sm & 7))<<3) + j0];
    dst[0]=(_Float16)xv0.x; dst[1]=(_Float16)xv0.y; dst[2]=(_Float16)xv0.z; dst[3]=(_Float16)xv0.w;
  }
  float cst[4] = {0.f,0.f,0.f,0.f};
  int r0 = lq*4;
  __syncthreads();
  for (int t = 0; t < SS; ++t) {
    int cur = t & 1, nxt = cur ^ 1;
    // prefetch x_{t+1}
    float4 xv;
    bool doPref = (tid < 256) && (t < SS-1);
    if (doPref) xv = *(const float4*)(wx + ((size_t)(b0+sm)*SS + (t+1))*FF + skq*4);
    // A fragments: lane holds A[m=lm][k=lq*8+j] per chunk
    h8 afr[6];
#pragma unroll
    for (int cc = 0; cc < 2; ++cc) {
      int kb = cc*4 + lq;
      afr[cc] = *(const h8*)&xst[cur][lm*64 + ((kb ^ (lm & 7))<<3)];
    }
#pragma unroll
    for (int cc = 0; cc < 4; ++cc) {
      int kb = cc*4 + lq;
      afr[2+cc] = *(const h8*)&hbuf[cur][lm*128 + ((kb ^ (lm & 7))<<3)];
    }
    f4v acc[4];
#pragma unroll
    for (int tt = 0; tt < 4; ++tt) {
      f4v a = {biasv[tt], biasv[tt], biasv[tt], biasv[tt]};
#pragma unroll
      for (int cc = 0; cc < 6; ++cc)
        a = __builtin_amdgcn_mfma_f32_16x16x32_f16(afr[cc], bfr[tt][cc], a, 0, 0, 0);
      acc[tt] = a;
    }
    // elementwise: lane has z_i/z_f/z_g/z_o for unit uu, rows r0..r0+3
#pragma unroll
    for (int r = 0; r < 4; ++r) {
      float zi = acc[0][r], zf = acc[1][r], zg = acc[2][r], zo = acc[3][r];
      float cn = sigmf(zf)*cst[r] + sigmf(zi)*tanhf(zg);
      float hn = sigmf(zo)*tanhf(cn);
      cst[r] = cn;
      int mr = r0 + r;
      if (uvalid) {
        hbuf[nxt][mr*128 + (((uu>>3) ^ (mr&7))<<3) + (uu&7)] = (_Float16)hn;
        enc[((size_t)(b0+mr)*SS + t)*HH + uu] = hn;
      } else {
        hbuf[nxt][mr*128 + (((uu>>3) ^ (mr&7))<<3) + (uu&7)] = (_Float16)0.f;
      }
    }
    // store staged x_{t+1}
    if (doPref) {
      int kb = skq >> 1, j0 = (skq & 1)*4;
      _Float16* dst = &xst[nxt][sm*64 + ((kb ^ (sm & 7))<<3) + j0];
      dst[0]=(_Float16)xv.x; dst[1]=(_Float16)xv.y; dst[2]=(_Float16)xv.z; dst[3]=(_Float16)xv.w;
    }
    __syncthreads();
  }
}

// ------- ts/time_w softmax over S, ctx, bott, dh0, dc0, decpre; one block per batch -------
__global__ __launch_bounds__(256) void k_attn(const float* __restrict__ enc,
    const float* __restrict__ aW1, const float* __restrict__ ab1,
    const float* __restrict__ aW2, const float* __restrict__ ab2,
    const float* __restrict__ bW, const float* __restrict__ bb_,
    const float* __restrict__ h0W, const float* __restrict__ h0b,
    const float* __restrict__ c0W, const float* __restrict__ c0b,
    const float* __restrict__ dWih, const float* __restrict__ dbih, const float* __restrict__ dbhh,
    float* __restrict__ tw_out, float* __restrict__ dh0, float* __restrict__ dc0,
    float* __restrict__ decpre){
  __shared__ float a1t[100*64];
  __shared__ float a2s[64], ab1s[64];
  __shared__ float tsb[SS];
  __shared__ float ctxb[HH];
  __shared__ float bottb[32];
  __shared__ float red[8];
  int tid = threadIdx.x, wv = tid>>6, lane = tid&63;
  int b = blockIdx.x;
  const float* encb = enc + (size_t)b*SS*HH;
  for (int i=tid;i<6400;i+=256){ int jj=i/100,k=i%100; a1t[k*64+jj]=aW1[i]; }
  if (tid<64){ a2s[tid]=aW2[tid]; ab1s[tid]=ab1[tid]; }
  __syncthreads();
  float ab2v = ab2[0];
  for (int si=0; si<32; ++si){
    int s = wv*32+si;
    const float4* er = (const float4*)(encb + s*HH);
    float a = ab1s[lane];
#pragma unroll
    for (int kc=0;kc<25;++kc){
      float4 e = er[kc];
      a += e.x*a1t[(kc*4+0)*64+lane] + e.y*a1t[(kc*4+1)*64+lane]
         + e.z*a1t[(kc*4+2)*64+lane] + e.w*a1t[(kc*4+3)*64+lane];
    }
    float contrib = a2s[lane]*tanhf(a);
    float t = wsum(contrib);
    if (lane==0) tsb[s] = t + ab2v;
  }
  __syncthreads();
  float tv = (tid < SS) ? tsb[tid] : -1e30f;
  float m = wmax(tv);
  if (lane==0) red[wv]=m;
  __syncthreads();
  m = fmaxf(fmaxf(red[0],red[1]), fmaxf(red[2],red[3]));
  float e = (tid < SS) ? __expf(tv - m) : 0.f;
  float sm = wsum(e);
  if (lane==0) red[4+wv]=sm;
  __syncthreads();
  float denom = red[4]+red[5]+red[6]+red[7];
  if (tid < SS){
    float twv = e/denom;
    tw_out[(size_t)b*SS + tid] = twv;
    tsb[tid] = twv;
  }
  __syncthreads();
  if (tid < HH){
    float a = 0.f;
    for (int s=0;s<SS;++s) a += tsb[s]*encb[s*HH + tid];
    ctxb[tid]=a;
  }
  __syncthreads();
  if (tid < 32){
    float a = bb_[tid];
    const float* wr = bW + tid*HH;
    for (int k=0;k<HH;++k) a += wr[k]*ctxb[k];
    bottb[tid]=a;
  }
  __syncthreads();
  if (tid < HH){
    float a = h0b[tid];
    const float* wr = h0W + tid*32;
#pragma unroll
    for (int k=0;k<32;++k) a += wr[k]*bottb[k];
    dh0[(size_t)b*HH + tid] = a;
  } else if (tid < 200){
    int jj = tid-100;
    float a = c0b[jj];
    const float* wr = c0W + jj*32;
#pragma unroll
    for (int k=0;k<32;++k) a += wr[k]*bottb[k];
    dc0[(size_t)b*HH + jj] = a;
  }
  {
    int jj = tid;
    float a = dbih[jj]+dbhh[jj];
    const float* wr = dWih + jj*32;
#pragma unroll
    for (int k=0;k<32;++k) a += wr[k]*bottb[k];
    decpre[(size_t)b*400 + jj] = a;
    jj = tid + 256;
    if (jj < 400){
      float a2v = dbih[jj]+dbhh[jj];
      const float* wr2 = dWih + jj*32;
#pragma unroll
      for (int k=0;k<32;++k) a2v += wr2[k]*bottb[k];
      decpre[(size_t)b*400 + jj] = a2v;
    }
  }
}

// ================= MFMA decoder LSTM =================
// Same structure as encoder but no x chunks (input transform precomputed in
// decpre, used as the accumulator init each step).
__global__ __launch_bounds__(448, 2) void k_dec_mfma(const float* __restrict__ decpre,
    const float* __restrict__ Whh,
    const float* __restrict__ dh0, const float* __restrict__ dc0,
    float* __restrict__ dec){
  __shared__ __align__(16) _Float16 hbuf[2][16*128];
  int tid = threadIdx.x;
  int w = tid >> 6, l = tid & 63;
  int lm = l & 15, lq = l >> 4;
  int b0 = blockIdx.x * 16;
  int uu = w*16 + lm;
  bool uvalid = uu < 100;
  int r0 = lq*4;
  h8 bfr[4][4];
#pragma unroll
  for (int tt = 0; tt < 4; ++tt) {
    int row = tt*100 + uu;
#pragma unroll
    for (int cc = 0; cc < 4; ++cc) {
      h8 f;
#pragma unroll
      for (int j = 0; j < 8; ++j) {
        int kh = cc*32 + lq*8 + j;
        float v = (uvalid && kh < 100) ? Whh[(size_t)row*100 + kh] : 0.f;
        f[j] = (_Float16)v;
      }
      bfr[tt][cc] = f;
    }
  }
  // pre-accumulator (decpre) and c/h state init
  f4v pre[4];
  float cst[4] = {0.f,0.f,0.f,0.f};
#pragma unroll
  for (int tt = 0; tt < 4; ++tt) {
#pragma unroll
    for (int r = 0; r < 4; ++r)
      pre[tt][r] = uvalid ? decpre[(size_t)(b0+r0+r)*400 + tt*100 + uu] : 0.f;
  }
  if (uvalid) {
#pragma unroll
    for (int r = 0; r < 4; ++r) cst[r] = dc0[(size_t)(b0+r0+r)*HH + uu];
  }
  // zero phase 1 first (anti-NaN: units 112..127 are never written in-loop),
  // then fill phase 0 with dh0.
  for (int i = tid; i < 16*128; i += 448) hbuf[1][i] = (_Float16)0.f;
  for (int idx = tid; idx < 16*128; idx += 448) {
    int m = idx >> 7, u2 = idx & 127;
    float v = (u2 < 100) ? dh0[(size_t)(b0+m)*HH + u2] : 0.f;
    hbuf[0][m*128 + (((u2>>3) ^ (m&7))<<3) + (u2&7)] = (_Float16)v;
  }
  __syncthreads();
  for (int t = 0; t < SS; ++t) {
    int cur = t & 1, nxt = cur ^ 1;
    h8 afr[4];
#pragma unroll
    for (int cc = 0; cc < 4; ++cc) {
      int kb = cc*4 + lq;
      afr[cc] = *(const h8*)&hbuf[cur][lm*128 + ((kb ^ (lm & 7))<<3)];
    }
    f4v acc[4];
#pragma unroll
    for (int tt = 0; tt < 4; ++tt) {
      f4v a = pre[tt];
#pragma unroll
      for (int cc = 0; cc < 4; ++cc)
        a = __builtin_amdgcn_mfma_f32_16x16x32_f16(afr[cc], bfr[tt][cc], a, 0, 0, 0);
      acc[tt] = a;
    }
#pragma unroll
    for (int r = 0; r < 4; ++r) {
      float zi = acc[0][r], zf = acc[1][r], zg = acc[2][r], zo = acc[3][r];
      float cn = sigmf(zf)*cst[r] + sigmf(zi)*tanhf(zg);
      float hn = sigmf(zo)*tanhf(cn);
      cst[r] = cn;
      int mr = r0 + r;
      if (uvalid) {
        hbuf[nxt][mr*128 + (((uu>>3) ^ (mr&7))<<3) + (uu&7)] = (_Float16)hn;
        dec[((size_t)(b0+mr)*SS + t)*HH + uu] = hn;
      } else {
        hbuf[nxt][mr*128 + (((uu>>3) ^ (mr&7))<<3) + (uu&7)] = (_Float16)0.f;
      }
    }
    __syncthreads();
  }
}

// ------------- out = dec @ oW^T + ob -------------
__global__ __launch_bounds__(256) void k_out(const float* __restrict__ dec,
    const float* __restrict__ oW, const float* __restrict__ ob, float* __restrict__ out0){
  __shared__ float oWt[100*64];
  __shared__ float dsr[64*100];
  int tid=threadIdx.x;
  size_t R0 = (size_t)blockIdx.x*64;
  for (int i=tid;i<6400;i+=256){ int j=i/100,k=i%100; oWt[k*64+j]=oW[i]; }
  for (int i=tid;i<6400;i+=256) dsr[i]=dec[R0*100 + i];
  __syncthreads();
  int j = tid&63, rb = tid>>6;
  float acc[16];
#pragma unroll
  for (int i=0;i<16;++i) acc[i]=0.f;
  for (int k=0;k<100;++k){
    float w = oWt[k*64+j];
#pragma unroll
    for (int i=0;i<16;++i) acc[i] += w*dsr[(rb + i*4)*100 + k];
  }
  float obv = ob[j];
#pragma unroll
  for (int i=0;i<16;++i) out0[(R0 + rb + i*4)*64 + j] = acc[i] + obv;
}

extern "C" void kernel_launch(void* const* d_in, const int* in_sizes, int n_in,
                              void* d_out, int out_size, void* d_ws, size_t ws_size,
                              hipStream_t stream) {
  const float* x    = (const float*)d_in[0];
  const float* c1w  = (const float*)d_in[1];
  const float* c1b  = (const float*)d_in[2];
  const float* c2w  = (const float*)d_in[3];
  const float* c2b  = (const float*)d_in[4];
  const float* fW1  = (const float*)d_in[5];
  const float* fb1  = (const float*)d_in[6];
  const float* fW2  = (const float*)d_in[7];
  const float* fb2  = (const float*)d_in[8];
  const float* cW1  = (const float*)d_in[9];
  const float* cb1  = (const float*)d_in[10];
  const float* cW2  = (const float*)d_in[11];
  const float* cb2  = (const float*)d_in[12];
  const float* eWih = (const float*)d_in[13];
  const float* eWhh = (const float*)d_in[14];
  const float* ebih = (const float*)d_in[15];
  const float* ebhh = (const float*)d_in[16];
  const float* aW1  = (const float*)d_in[17];
  const float* ab1  = (const float*)d_in[18];
  const float* aW2  = (const float*)d_in[19];
  const float* ab2  = (const float*)d_in[20];
  const float* bW   = (const float*)d_in[21];
  const float* bb   = (const float*)d_in[22];
  const float* h0W  = (const float*)d_in[23];
  const float* h0b  = (const float*)d_in[24];
  const float* c0W  = (const float*)d_in[25];
  const float* c0b  = (const float*)d_in[26];
  const float* dWih = (const float*)d_in[27];
  const float* dWhh = (const float*)d_in[28];
  const float* dbih = (const float*)d_in[29];
  const float* dbhh = (const float*)d_in[30];
  const float* oW   = (const float*)d_in[31];
  const float* ob   = (const float*)d_in[32];

  float* out0   = (float*)d_out;
  float* out_tw = out0 + (size_t)BB*SS*FF;
  float* out_fw = out_tw + (size_t)BB*SS;

  char* ws = (char*)d_ws;
  float*  gram   = (float*) (ws + 0);           // 16.78 MB
  __half* pool1  = (__half*)(ws + 16777216);    // 33.55 MB
  float*  proc   = (float*) (ws + 50331648);    // 0.13 MB
  float*  fsbuf  = (float*) (ws + 50462720);    // 33.55 MB
  float*  wx     = (float*) (ws + 84017152);    // 33.55 MB
  float*  enc    = (float*) (ws + 117571584);   // 52.43 MB
  float*  dh0    = (float*) (ws + 170000384);   // 0.41 MB
  float*  dc0    = (float*) (ws + 170409984);   // 0.41 MB
  float*  decpre = (float*) (ws + 170819584);   // 1.64 MB
  float*  dec    = (float*) (ws + 172457984);   // 52.43 MB  (end ~224.9 MB)

  k_gram<<<BB, 256, 0, stream>>>(x, gram);
  k_conv1pool<<<BB, 256, 0, stream>>>(gram, c1w, c1b, pool1);
  k_conv2mean<<<BB, 512, 0, stream>>>(pool1, c2w, c2b, proc);
  k_fs<<<2048, 256, 0, stream>>>(x, fW1, fb1, fW2, fb2, fsbuf);
  k_attnmlp<<<2048, 256, 0, stream>>>(x, fsbuf, proc, cW1, cb1, cW2, cb2, out_fw, wx);
  k_enc_mfma<<<64, 448, 0, stream>>>(wx, eWih, eWhh, ebih, ebhh, enc);
  k_attn<<<BB, 256, 0, stream>>>(enc, aW1, ab1, aW2, ab2, bW, bb, h0W, h0b, c0W, c0b,
                                 dWih, dbih, dbhh, out_tw, dh0, dc0, decpre);
  k_dec_mfma<<<64, 448, 0, stream>>>(decpre, dWhh, dh0, dc0, dec);
  k_out<<<2048, 256, 0, stream>>>(dec, oW, ob, out0);
}

// Round 4
// 1170.990 us; speedup vs baseline: 1.6766x; 1.1976x over previous
//
#include <hip/hip_runtime.h>
#include <hip/hip_fp16.h>

#define BB 1024
#define SS 128
#define FF 64
#define HH 100

typedef _Float16 h8 __attribute__((ext_vector_type(8)));
typedef float f4v __attribute__((ext_vector_type(4)));

__device__ __forceinline__ float sigmf(float x){ return 1.0f/(1.0f+__expf(-x)); }

__device__ __forceinline__ float wsum(float v){
#pragma unroll
  for (int m = 32; m >= 1; m >>= 1) v += __shfl_xor(v, m, 64);
  return v;
}
__device__ __forceinline__ float wmax(float v){
#pragma unroll
  for (int m = 32; m >= 1; m >>= 1) v = fmaxf(v, __shfl_xor(v, m, 64));
  return v;
}

// ---------------- gram: gram[b,i,j] = sum_s x[b,s,i]*x[b,s,j] ----------------
__global__ __launch_bounds__(256) void k_gram(const float* __restrict__ x, float* __restrict__ gram){
  __shared__ __align__(16) float xs[SS*FF];
  int b = blockIdx.x, tid = threadIdx.x;
  const float* xb = x + (size_t)b*SS*FF;
  for (int i = tid; i < SS*FF/4; i += 256)
    ((float4*)xs)[i] = ((const float4*)xb)[i];
  __syncthreads();
  int ti = (tid & 15) * 4, tj = (tid >> 4) * 4;
  float acc[4][4];
#pragma unroll
  for (int a=0;a<4;++a)
#pragma unroll
    for (int c=0;c<4;++c) acc[a][c]=0.f;
  for (int s = 0; s < SS; ++s) {
    const float* row = xs + s*FF;
    float4 av = *(const float4*)(row + ti);
    float4 bv = *(const float4*)(row + tj);
    float aa[4] = {av.x,av.y,av.z,av.w};
    float bb2[4] = {bv.x,bv.y,bv.z,bv.w};
#pragma unroll
    for (int a=0;a<4;++a)
#pragma unroll
      for (int c=0;c<4;++c) acc[a][c] += aa[a]*bb2[c];
  }
  float* g = gram + (size_t)b*4096;
#pragma unroll
  for (int a=0;a<4;++a)
#pragma unroll
    for (int c=0;c<4;++c) g[(ti+a)*64 + tj + c] = acc[a][c];
}

// ------- conv1(3x3,1->16,SAME)+bias+relu+maxpool2 -> half CHANNEL-LAST [B][p][ic] -------
__global__ __launch_bounds__(256) void k_conv1pool(const float* __restrict__ gram,
    const float* __restrict__ c1w, const float* __restrict__ c1b, __half* __restrict__ pool1){
  __shared__ float img2[66*66];
  __shared__ float ws1[144];
  __shared__ float bs1[16];
  int tid=threadIdx.x, b=blockIdx.x;
  for (int i=tid;i<66*66;i+=256) img2[i]=0.f;
  if (tid<144) ws1[tid]=c1w[tid];
  if (tid<16) bs1[tid]=c1b[tid];
  __syncthreads();
  const float* gb = gram + (size_t)b*4096;
  for (int i=tid;i<4096;i+=256){ int y=i>>6, xx=i&63; img2[(y+1)*66 + xx+1] = gb[i]; }
  __syncthreads();
  int oc = tid>>4, slot = tid&15;
  float wr[9];
#pragma unroll
  for (int t=0;t<9;++t) wr[t]=ws1[oc*9+t];
  float bo = bs1[oc];
  for (int p=slot;p<1024;p+=16){
    int py=p>>5, px=p&31;
    int y0=py*2, x0=px*2;
    float v[4][4];
#pragma unroll
    for (int wy=0;wy<4;++wy)
#pragma unroll
      for (int wxx=0;wxx<4;++wxx) v[wy][wxx]=img2[(y0+wy)*66 + x0+wxx];
    float s00=bo,s01=bo,s10=bo,s11=bo;
#pragma unroll
    for (int ky=0;ky<3;++ky)
#pragma unroll
      for (int kx=0;kx<3;++kx){
        float w=wr[ky*3+kx];
        s00 += v[ky][kx]*w;   s01 += v[ky][kx+1]*w;
        s10 += v[ky+1][kx]*w; s11 += v[ky+1][kx+1]*w;
      }
    float mx = fmaxf(fmaxf(s00,s01),fmaxf(s10,s11));
    // channel-last layout for conv2's im2col-free MFMA staging
    pool1[(size_t)b*16384 + p*16 + oc] = __float2half(fmaxf(mx,0.f));
  }
}

// ================= conv2 as implicit-im2col MFMA GEMM =================
// Per block = one image. LDS image channel-last f16 [34pad x 34pad x 16ic],
// pixel stride 24 halves (48 B). K = tap*16+ic (160 padded, 5 chunks of 32):
// A-fragment = ONE ds_read_b128 per lane per chunk (lq>>1 selects tap parity,
// lq&1 selects ic half, lm selects pixel). B (weights) in VGPRs.
// C rows = pixels; relu+sum in registers -> spatial mean.
__global__ __launch_bounds__(512, 4) void k_conv2mfma(const __half* __restrict__ pool1,
    const float* __restrict__ c2w, const float* __restrict__ c2b, float* __restrict__ proc){
  __shared__ __align__(16) _Float16 img[(34*34+1)*24];   // +1 zero slot
  __shared__ float red[8][32];
  int b = blockIdx.x, tid = threadIdx.x;
  int wv = tid>>6, l = tid&63, lm = l&15, lq = l>>4;
  // ---- B fragments: bfr[nt][c][j] = Wk[k=32c+lq*8+j][oc=nt*16+lm] ----
  h8 bfr[2][5];
  float biasv[2];
#pragma unroll
  for (int nt=0; nt<2; ++nt){
    int oc = nt*16 + lm;
    biasv[nt] = c2b[oc];
#pragma unroll
    for (int c=0;c<5;++c){
      h8 f;
#pragma unroll
      for (int j=0;j<8;++j){
        int k = c*32 + lq*8 + j;
        int tap = k>>4, ic = k&15;
        f[j] = (_Float16)((tap<9) ? c2w[oc*144 + ic*9 + tap] : 0.f);
      }
      bfr[nt][c]=f;
    }
  }
  // ---- zero whole image buffer (borders + zero slot), then fill interior ----
  {
    h8 z = {0,0,0,0,0,0,0,0};
    for (int i=tid; i<(34*34+1)*3; i+=512) ((h8*)img)[i] = z;
  }
  __syncthreads();
  const __half* src = pool1 + (size_t)b*16384;
  for (int pp=tid; pp<1024; pp+=512){
    int y=pp>>5, x=pp&31;
    const h8* s = (const h8*)(src + pp*16);
    h8* d = (h8*)&img[((y+1)*34 + (x+1))*24];
    d[0]=s[0]; d[1]=s[1];
  }
  __syncthreads();
  // ---- main: 8 M-tiles per wave, 5 chunks x 2 N-tiles MFMA each ----
  f4v ssum0 = {0,0,0,0}, ssum1 = {0,0,0,0};
#pragma unroll 2
  for (int i=0;i<8;++i){
    int mt = wv + i*8;                 // M-tile 0..63; pixel p = mt*16 + m
    int y = mt>>1, x0 = (mt&1)*16;
    h8 afr[5];
#pragma unroll
    for (int c=0;c<5;++c){
      int tap = 2*c + (lq>>1);
      int addr;
      if (c==4 && lq>=2) addr = 34*34*24;   // zero slot (k >= 144 pad)
      else {
        int dy = tap/3 - 1, dx = tap - (tap/3)*3 - 1;
        addr = ((y+dy+1)*34 + (x0+lm+dx+1))*24 + (lq&1)*8;
      }
      afr[c] = *(const h8*)&img[addr];
    }
    f4v a0 = {biasv[0],biasv[0],biasv[0],biasv[0]};
    f4v a1 = {biasv[1],biasv[1],biasv[1],biasv[1]};
#pragma unroll
    for (int c=0;c<5;++c){
      a0 = __builtin_amdgcn_mfma_f32_16x16x32_f16(afr[c], bfr[0][c], a0, 0,0,0);
      a1 = __builtin_amdgcn_mfma_f32_16x16x32_f16(afr[c], bfr[1][c], a1, 0,0,0);
    }
#pragma unroll
    for (int r=0;r<4;++r){
      ssum0[r] += fmaxf(a0[r],0.f);
      ssum1[r] += fmaxf(a1[r],0.f);
    }
  }
  float s0 = ssum0[0]+ssum0[1]+ssum0[2]+ssum0[3];
  float s1 = ssum1[0]+ssum1[1]+ssum1[2]+ssum1[3];
  s0 += __shfl_xor(s0,16,64); s0 += __shfl_xor(s0,32,64);
  s1 += __shfl_xor(s1,16,64); s1 += __shfl_xor(s1,32,64);
  if (lq==0){ red[wv][lm]=s0; red[wv][16+lm]=s1; }
  __syncthreads();
  if (tid<32){
    float t=0.f;
#pragma unroll
    for (int w2=0;w2<8;++w2) t += red[w2][tid];
    proc[b*32+tid] = t*(1.f/1024.f);
  }
}

// ------------- fs = tanh(x@fW1^T+fb1)@fW2^T+fb2, per (b,s) row -------------
__global__ __launch_bounds__(256) void k_fs(const float* __restrict__ x,
    const float* __restrict__ fW1, const float* __restrict__ fb1,
    const float* __restrict__ fW2, const float* __restrict__ fb2,
    float* __restrict__ fs){
  __shared__ float w1t[64*32];   // w1t[k*32+j] = fW1[j*64+k]
  __shared__ float w2t[32*64];   // w2t[k*64+j] = fW2[j*32+k]
  __shared__ float b1s[32], b2s[64];
  __shared__ __align__(16) float xbuf[4][8][64];
  __shared__ float t1buf[4][8][32];
  int tid=threadIdx.x, wv=tid>>6, lane=tid&63;
  for (int i=tid;i<2048;i+=256){ int j=i>>6,k=i&63; w1t[k*32+j]=fW1[i]; }
  for (int i=tid;i<2048;i+=256){ int j=i>>5,k=i&31; w2t[k*64+j]=fW2[i]; }
  if (tid<32) b1s[tid]=fb1[tid];
  if (tid<64) b2s[tid]=fb2[tid];
  __syncthreads();
  size_t Rw = (size_t)blockIdx.x*64 + wv*16;
  int j = lane & 31, half = lane >> 5;
  for (int pass=0; pass<2; ++pass){
    size_t R0 = Rw + pass*8;
    const float4* src = (const float4*)(x + R0*64);
    float4* dst = (float4*)&xbuf[wv][0][0];
    for (int i=lane;i<128;i+=64) dst[i]=src[i];
    __syncthreads();
    {
      float a0=b1s[j],a1=b1s[j],a2=b1s[j],a3=b1s[j];
      const float* xr = &xbuf[wv][half*4][0];
      for (int k=0;k<64;++k){
        float w = w1t[k*32+j];
        a0 += w*xr[k]; a1 += w*xr[64+k]; a2 += w*xr[128+k]; a3 += w*xr[192+k];
      }
      float* t1r = &t1buf[wv][half*4][0];
      t1r[j]=tanhf(a0); t1r[32+j]=tanhf(a1); t1r[64+j]=tanhf(a2); t1r[96+j]=tanhf(a3);
    }
    __syncthreads();
    {
      float f[8];
#pragma unroll
      for (int r=0;r<8;++r) f[r]=b2s[lane];
      for (int k=0;k<32;++k){
        float w = w2t[k*64+lane];
#pragma unroll
        for (int r=0;r<8;++r) f[r] += w*t1buf[wv][r][k];
      }
#pragma unroll
      for (int r=0;r<8;++r) fs[(R0+r)*64 + lane] = f[r];
    }
    __syncthreads();
  }
}

// ------- aw = tanh([fs,proc]@cW1^T+cb1)@cW2^T+cb2; feature_w=softmax(aw); wx=x*fw -------
__global__ __launch_bounds__(256) void k_attnmlp(const float* __restrict__ x,
    const float* __restrict__ fs, const float* __restrict__ proc,
    const float* __restrict__ cW1, const float* __restrict__ cb1,
    const float* __restrict__ cW2, const float* __restrict__ cb2,
    float* __restrict__ fw_out, float* __restrict__ wx){
  __shared__ float c1t[96*64];
  __shared__ float c2t[64*64];
  __shared__ float cb1s[64], cb2s[64];
  __shared__ float cmb[4][4][96];
  __shared__ float h2b[4][4][64];
  int tid = threadIdx.x, wv = tid>>6, lane = tid&63;
  for (int i = tid; i < 6144; i += 256){ int j = i/96, k = i%96; c1t[k*64+j] = cW1[i]; }
  for (int i = tid; i < 4096; i += 256){ int j = i>>6, k = i&63; c2t[k*64+j] = cW2[i]; }
  if (tid < 64) { cb1s[tid] = cb1[tid]; cb2s[tid] = cb2[tid]; }
  __syncthreads();
  size_t Rw = (size_t)blockIdx.x*64 + wv*16;
  for (int pass = 0; pass < 4; ++pass) {
    size_t R0 = Rw + pass*4;
    for (int i = lane; i < 384; i += 64) {
      int r = i/96, k = i%96;
      size_t R = R0 + r;
      cmb[wv][r][k] = (k < 64) ? fs[R*64 + k] : proc[(R>>7)*32 + (k-64)];
    }
    __syncthreads();
    float h0a=cb1s[lane],h1a=cb1s[lane],h2a=cb1s[lane],h3a=cb1s[lane];
    for (int k = 0; k < 96; ++k) {
      float w = c1t[k*64+lane];
      h0a += w*cmb[wv][0][k]; h1a += w*cmb[wv][1][k];
      h2a += w*cmb[wv][2][k]; h3a += w*cmb[wv][3][k];
    }
    h2b[wv][0][lane]=tanhf(h0a); h2b[wv][1][lane]=tanhf(h1a);
    h2b[wv][2][lane]=tanhf(h2a); h2b[wv][3][lane]=tanhf(h3a);
    __syncthreads();
    float a0=cb2s[lane],a1=cb2s[lane],a2=cb2s[lane],a3=cb2s[lane];
    for (int k = 0; k < 64; ++k) {
      float w = c2t[k*64+lane];
      a0 += w*h2b[wv][0][k]; a1 += w*h2b[wv][1][k];
      a2 += w*h2b[wv][2][k]; a3 += w*h2b[wv][3][k];
    }
    float m0=wmax(a0), m1=wmax(a1), m2=wmax(a2), m3=wmax(a3);
    float e0=__expf(a0-m0), e1=__expf(a1-m1), e2=__expf(a2-m2), e3=__expf(a3-m3);
    float s0=wsum(e0), s1=wsum(e1), s2=wsum(e2), s3=wsum(e3);
    float f0v=e0/s0, f1v=e1/s1, f2v=e2/s2, f3v=e3/s3;
    size_t R;
    R=R0+0; fw_out[R*64+lane]=f0v; wx[R*64+lane]=x[R*64+lane]*f0v;
    R=R0+1; fw_out[R*64+lane]=f1v; wx[R*64+lane]=x[R*64+lane]*f1v;
    R=R0+2; fw_out[R*64+lane]=f2v; wx[R*64+lane]=x[R*64+lane]*f2v;
    R=R0+3; fw_out[R*64+lane]=f3v; wx[R*64+lane]=x[R*64+lane]*f3v;
    __syncthreads();
  }
}

// ================= MFMA encoder LSTM =================
// 64 blocks x 448 threads (7 waves). Block owns 16 batch rows; wave w owns
// units [16w,16w+16) for all 4 gates (4 N-tiles). Weights live in VGPRs.
// NOTE: BOTH hbuf phases must be zeroed — units 112..127 are owned by no
// wave and are read (against zero weights) every step; stale LDS there was
// the R2 NaN (garbage f16 can be Inf/NaN, and NaN*0 = NaN in MFMA).
__global__ __launch_bounds__(448, 2) void k_enc_mfma(const float* __restrict__ wx,
    const float* __restrict__ Wih, const float* __restrict__ Whh,
    const float* __restrict__ bih, const float* __restrict__ bhh,
    float* __restrict__ enc){
  __shared__ __align__(16) _Float16 hbuf[2][16*128];
  __shared__ __align__(16) _Float16 xst[2][16*64];
  int tid = threadIdx.x;
  int w = tid >> 6, l = tid & 63;
  int lm = l & 15, lq = l >> 4;
  int b0 = blockIdx.x * 16;
  // ---- load B fragments (weights) into registers, f32 -> f16 ----
  h8 bfr[4][6];
  float biasv[4];
  int uu = w*16 + lm;
  bool uvalid = uu < 100;
#pragma unroll
  for (int tt = 0; tt < 4; ++tt) {
    int row = tt*100 + uu;
    biasv[tt] = uvalid ? (bih[row] + bhh[row]) : 0.f;
#pragma unroll
    for (int cc = 0; cc < 6; ++cc) {
      h8 f;
#pragma unroll
      for (int j = 0; j < 8; ++j) {
        int kg = cc*32 + lq*8 + j;
        float v = 0.f;
        if (uvalid) {
          if (kg < 64) v = Wih[(size_t)row*64 + kg];
          else { int kh = kg - 64; if (kh < 100) v = Whh[(size_t)row*100 + kh]; }
        }
        f[j] = (_Float16)v;
      }
      bfr[tt][cc] = f;
    }
  }
  // zero BOTH h buffers and xst[1] (anti-NaN: no stale LDS may reach MFMA)
  for (int i = tid; i < 2*16*128; i += 448) hbuf[0][i] = (_Float16)0.f;
  for (int i = tid; i < 16*64; i += 448) xst[1][i] = (_Float16)0.f;
  // stage x_0 (threads 0..255: one float4 each)
  int sm = tid >> 4, skq = tid & 15;
  __syncthreads();
  if (tid < 256) {
    float4 xv0 = *(const float4*)(wx + ((size_t)(b0+sm)*SS + 0)*FF + skq*4);
    int kb = skq >> 1, j0 = (skq & 1)*4;
    _Float16* dst = &xst[0][sm*64 + ((kb ^ (sm & 7))<<3) + j0];
    dst[0]=(_Float16)xv0.x; dst[1]=(_Float16)xv0.y; dst[2]=(_Float16)xv0.z; dst[3]=(_Float16)xv0.w;
  }
  float cst[4] = {0.f,0.f,0.f,0.f};
  int r0 = lq*4;
  __syncthreads();
  for (int t = 0; t < SS; ++t) {
    int cur = t & 1, nxt = cur ^ 1;
    // prefetch x_{t+1}
    float4 xv;
    bool doPref = (tid < 256) && (t < SS-1);
    if (doPref) xv = *(const float4*)(wx + ((size_t)(b0+sm)*SS + (t+1))*FF + skq*4);
    // A fragments: lane holds A[m=lm][k=lq*8+j] per chunk
    h8 afr[6];
#pragma unroll
    for (int cc = 0; cc < 2; ++cc) {
      int kb = cc*4 + lq;
      afr[cc] = *(const h8*)&xst[cur][lm*64 + ((kb ^ (lm & 7))<<3)];
    }
#pragma unroll
    for (int cc = 0; cc < 4; ++cc) {
      int kb = cc*4 + lq;
      afr[2+cc] = *(const h8*)&hbuf[cur][lm*128 + ((kb ^ (lm & 7))<<3)];
    }
    f4v acc[4];
#pragma unroll
    for (int tt = 0; tt < 4; ++tt) {
      f4v a = {biasv[tt], biasv[tt], biasv[tt], biasv[tt]};
#pragma unroll
      for (int cc = 0; cc < 6; ++cc)
        a = __builtin_amdgcn_mfma_f32_16x16x32_f16(afr[cc], bfr[tt][cc], a, 0, 0, 0);
      acc[tt] = a;
    }
    // elementwise: lane has z_i/z_f/z_g/z_o for unit uu, rows r0..r0+3
#pragma unroll
    for (int r = 0; r < 4; ++r) {
      float zi = acc[0][r], zf = acc[1][r], zg = acc[2][r], zo = acc[3][r];
      float cn = sigmf(zf)*cst[r] + sigmf(zi)*tanhf(zg);
      float hn = sigmf(zo)*tanhf(cn);
      cst[r] = cn;
      int mr = r0 + r;
      if (uvalid) {
        hbuf[nxt][mr*128 + (((uu>>3) ^ (mr&7))<<3) + (uu&7)] = (_Float16)hn;
        enc[((size_t)(b0+mr)*SS + t)*HH + uu] = hn;
      } else {
        hbuf[nxt][mr*128 + (((uu>>3) ^ (mr&7))<<3) + (uu&7)] = (_Float16)0.f;
      }
    }
    // store staged x_{t+1}
    if (doPref) {
      int kb = skq >> 1, j0 = (skq & 1)*4;
      _Float16* dst = &xst[nxt][sm*64 + ((kb ^ (sm & 7))<<3) + j0];
      dst[0]=(_Float16)xv.x; dst[1]=(_Float16)xv.y; dst[2]=(_Float16)xv.z; dst[3]=(_Float16)xv.w;
    }
    __syncthreads();
  }
}

// ------- ts/time_w softmax over S, ctx, bott, dh0, dc0, decpre; one block per batch -------
__global__ __launch_bounds__(256) void k_attn(const float* __restrict__ enc,
    const float* __restrict__ aW1, const float* __restrict__ ab1,
    const float* __restrict__ aW2, const float* __restrict__ ab2,
    const float* __restrict__ bW, const float* __restrict__ bb_,
    const float* __restrict__ h0W, const float* __restrict__ h0b,
    const float* __restrict__ c0W, const float* __restrict__ c0b,
    const float* __restrict__ dWih, const float* __restrict__ dbih, const float* __restrict__ dbhh,
    float* __restrict__ tw_out, float* __restrict__ dh0, float* __restrict__ dc0,
    float* __restrict__ decpre){
  __shared__ float a1t[100*64];
  __shared__ float a2s[64], ab1s[64];
  __shared__ float tsb[SS];
  __shared__ float ctxb[HH];
  __shared__ float bottb[32];
  __shared__ float red[8];
  int tid = threadIdx.x, wv = tid>>6, lane = tid&63;
  int b = blockIdx.x;
  const float* encb = enc + (size_t)b*SS*HH;
  for (int i=tid;i<6400;i+=256){ int jj=i/100,k=i%100; a1t[k*64+jj]=aW1[i]; }
  if (tid<64){ a2s[tid]=aW2[tid]; ab1s[tid]=ab1[tid]; }
  __syncthreads();
  float ab2v = ab2[0];
  for (int si=0; si<32; ++si){
    int s = wv*32+si;
    const float4* er = (const float4*)(encb + s*HH);
    float a = ab1s[lane];
#pragma unroll
    for (int kc=0;kc<25;++kc){
      float4 e = er[kc];
      a += e.x*a1t[(kc*4+0)*64+lane] + e.y*a1t[(kc*4+1)*64+lane]
         + e.z*a1t[(kc*4+2)*64+lane] + e.w*a1t[(kc*4+3)*64+lane];
    }
    float contrib = a2s[lane]*tanhf(a);
    float t = wsum(contrib);
    if (lane==0) tsb[s] = t + ab2v;
  }
  __syncthreads();
  float tv = (tid < SS) ? tsb[tid] : -1e30f;
  float m = wmax(tv);
  if (lane==0) red[wv]=m;
  __syncthreads();
  m = fmaxf(fmaxf(red[0],red[1]), fmaxf(red[2],red[3]));
  float e = (tid < SS) ? __expf(tv - m) : 0.f;
  float sm = wsum(e);
  if (lane==0) red[4+wv]=sm;
  __syncthreads();
  float denom = red[4]+red[5]+red[6]+red[7];
  if (tid < SS){
    float twv = e/denom;
    tw_out[(size_t)b*SS + tid] = twv;
    tsb[tid] = twv;
  }
  __syncthreads();
  if (tid < HH){
    float a = 0.f;
    for (int s=0;s<SS;++s) a += tsb[s]*encb[s*HH + tid];
    ctxb[tid]=a;
  }
  __syncthreads();
  if (tid < 32){
    float a = bb_[tid];
    const float* wr = bW + tid*HH;
    for (int k=0;k<HH;++k) a += wr[k]*ctxb[k];
    bottb[tid]=a;
  }
  __syncthreads();
  if (tid < HH){
    float a = h0b[tid];
    const float* wr = h0W + tid*32;
#pragma unroll
    for (int k=0;k<32;++k) a += wr[k]*bottb[k];
    dh0[(size_t)b*HH + tid] = a;
  } else if (tid < 200){
    int jj = tid-100;
    float a = c0b[jj];
    const float* wr = c0W + jj*32;
#pragma unroll
    for (int k=0;k<32;++k) a += wr[k]*bottb[k];
    dc0[(size_t)b*HH + jj] = a;
  }
  {
    int jj = tid;
    float a = dbih[jj]+dbhh[jj];
    const float* wr = dWih + jj*32;
#pragma unroll
    for (int k=0;k<32;++k) a += wr[k]*bottb[k];
    decpre[(size_t)b*400 + jj] = a;
    jj = tid + 256;
    if (jj < 400){
      float a2v = dbih[jj]+dbhh[jj];
      const float* wr2 = dWih + jj*32;
#pragma unroll
      for (int k=0;k<32;++k) a2v += wr2[k]*bottb[k];
      decpre[(size_t)b*400 + jj] = a2v;
    }
  }
}

// ================= MFMA decoder LSTM =================
// Same structure as encoder but no x chunks (input transform precomputed in
// decpre, used as the accumulator init each step).
__global__ __launch_bounds__(448, 2) void k_dec_mfma(const float* __restrict__ decpre,
    const float* __restrict__ Whh,
    const float* __restrict__ dh0, const float* __restrict__ dc0,
    float* __restrict__ dec){
  __shared__ __align__(16) _Float16 hbuf[2][16*128];
  int tid = threadIdx.x;
  int w = tid >> 6, l = tid & 63;
  int lm = l & 15, lq = l >> 4;
  int b0 = blockIdx.x * 16;
  int uu = w*16 + lm;
  bool uvalid = uu < 100;
  int r0 = lq*4;
  h8 bfr[4][4];
#pragma unroll
  for (int tt = 0; tt < 4; ++tt) {
    int row = tt*100 + uu;
#pragma unroll
    for (int cc = 0; cc < 4; ++cc) {
      h8 f;
#pragma unroll
      for (int j = 0; j < 8; ++j) {
        int kh = cc*32 + lq*8 + j;
        float v = (uvalid && kh < 100) ? Whh[(size_t)row*100 + kh] : 0.f;
        f[j] = (_Float16)v;
      }
      bfr[tt][cc] = f;
    }
  }
  // pre-accumulator (decpre) and c/h state init
  f4v pre[4];
  float cst[4] = {0.f,0.f,0.f,0.f};
#pragma unroll
  for (int tt = 0; tt < 4; ++tt) {
#pragma unroll
    for (int r = 0; r < 4; ++r)
      pre[tt][r] = uvalid ? decpre[(size_t)(b0+r0+r)*400 + tt*100 + uu] : 0.f;
  }
  if (uvalid) {
#pragma unroll
    for (int r = 0; r < 4; ++r) cst[r] = dc0[(size_t)(b0+r0+r)*HH + uu];
  }
  // zero phase 1 first (anti-NaN: units 112..127 are never written in-loop),
  // then fill phase 0 with dh0.
  for (int i = tid; i < 16*128; i += 448) hbuf[1][i] = (_Float16)0.f;
  for (int idx = tid; idx < 16*128; idx += 448) {
    int m = idx >> 7, u2 = idx & 127;
    float v = (u2 < 100) ? dh0[(size_t)(b0+m)*HH + u2] : 0.f;
    hbuf[0][m*128 + (((u2>>3) ^ (m&7))<<3) + (u2&7)] = (_Float16)v;
  }
  __syncthreads();
  for (int t = 0; t < SS; ++t) {
    int cur = t & 1, nxt = cur ^ 1;
    h8 afr[4];
#pragma unroll
    for (int cc = 0; cc < 4; ++cc) {
      int kb = cc*4 + lq;
      afr[cc] = *(const h8*)&hbuf[cur][lm*128 + ((kb ^ (lm & 7))<<3)];
    }
    f4v acc[4];
#pragma unroll
    for (int tt = 0; tt < 4; ++tt) {
      f4v a = pre[tt];
#pragma unroll
      for (int cc = 0; cc < 4; ++cc)
        a = __builtin_amdgcn_mfma_f32_16x16x32_f16(afr[cc], bfr[tt][cc], a, 0, 0, 0);
      acc[tt] = a;
    }
#pragma unroll
    for (int r = 0; r < 4; ++r) {
      float zi = acc[0][r], zf = acc[1][r], zg = acc[2][r], zo = acc[3][r];
      float cn = sigmf(zf)*cst[r] + sigmf(zi)*tanhf(zg);
      float hn = sigmf(zo)*tanhf(cn);
      cst[r] = cn;
      int mr = r0 + r;
      if (uvalid) {
        hbuf[nxt][mr*128 + (((uu>>3) ^ (mr&7))<<3) + (uu&7)] = (_Float16)hn;
        dec[((size_t)(b0+mr)*SS + t)*HH + uu] = hn;
      } else {
        hbuf[nxt][mr*128 + (((uu>>3) ^ (mr&7))<<3) + (uu&7)] = (_Float16)0.f;
      }
    }
    __syncthreads();
  }
}

// ------------- out = dec @ oW^T + ob -------------
__global__ __launch_bounds__(256) void k_out(const float* __restrict__ dec,
    const float* __restrict__ oW, const float* __restrict__ ob, float* __restrict__ out0){
  __shared__ float oWt[100*64];
  __shared__ float dsr[64*100];
  int tid=threadIdx.x;
  size_t R0 = (size_t)blockIdx.x*64;
  for (int i=tid;i<6400;i+=256){ int j=i/100,k=i%100; oWt[k*64+j]=oW[i]; }
  for (int i=tid;i<6400;i+=256) dsr[i]=dec[R0*100 + i];
  __syncthreads();
  int j = tid&63, rb = tid>>6;
  float acc[16];
#pragma unroll
  for (int i=0;i<16;++i) acc[i]=0.f;
  for (int k=0;k<100;++k){
    float w = oWt[k*64+j];
#pragma unroll
    for (int i=0;i<16;++i) acc[i] += w*dsr[(rb + i*4)*100 + k];
  }
  float obv = ob[j];
#pragma unroll
  for (int i=0;i<16;++i) out0[(R0 + rb + i*4)*64 + j] = acc[i] + obv;
}

extern "C" void kernel_launch(void* const* d_in, const int* in_sizes, int n_in,
                              void* d_out, int out_size, void* d_ws, size_t ws_size,
                              hipStream_t stream) {
  const float* x    = (const float*)d_in[0];
  const float* c1w  = (const float*)d_in[1];
  const float* c1b  = (const float*)d_in[2];
  const float* c2w  = (const float*)d_in[3];
  const float* c2b  = (const float*)d_in[4];
  const float* fW1  = (const float*)d_in[5];
  const float* fb1  = (const float*)d_in[6];
  const float* fW2  = (const float*)d_in[7];
  const float* fb2  = (const float*)d_in[8];
  const float* cW1  = (const float*)d_in[9];
  const float* cb1  = (const float*)d_in[10];
  const float* cW2  = (const float*)d_in[11];
  const float* cb2  = (const float*)d_in[12];
  const float* eWih = (const float*)d_in[13];
  const float* eWhh = (const float*)d_in[14];
  const float* ebih = (const float*)d_in[15];
  const float* ebhh = (const float*)d_in[16];
  const float* aW1  = (const float*)d_in[17];
  const float* ab1  = (const float*)d_in[18];
  const float* aW2  = (const float*)d_in[19];
  const float* ab2  = (const float*)d_in[20];
  const float* bW   = (const float*)d_in[21];
  const float* bb   = (const float*)d_in[22];
  const float* h0W  = (const float*)d_in[23];
  const float* h0b  = (const float*)d_in[24];
  const float* c0W  = (const float*)d_in[25];
  const float* c0b  = (const float*)d_in[26];
  const float* dWih = (const float*)d_in[27];
  const float* dWhh = (const float*)d_in[28];
  const float* dbih = (const float*)d_in[29];
  const float* dbhh = (const float*)d_in[30];
  const float* oW   = (const float*)d_in[31];
  const float* ob   = (const float*)d_in[32];

  float* out0   = (float*)d_out;
  float* out_tw = out0 + (size_t)BB*SS*FF;
  float* out_fw = out_tw + (size_t)BB*SS;

  char* ws = (char*)d_ws;
  float*  gram   = (float*) (ws + 0);           // 16.78 MB
  __half* pool1  = (__half*)(ws + 16777216);    // 33.55 MB (channel-last [b][p][ic])
  float*  proc   = (float*) (ws + 50331648);    // 0.13 MB
  float*  fsbuf  = (float*) (ws + 50462720);    // 33.55 MB
  float*  wx     = (float*) (ws + 84017152);    // 33.55 MB
  float*  enc    = (float*) (ws + 117571584);   // 52.43 MB
  float*  dh0    = (float*) (ws + 170000384);   // 0.41 MB
  float*  dc0    = (float*) (ws + 170409984);   // 0.41 MB
  float*  decpre = (float*) (ws + 170819584);   // 1.64 MB
  float*  dec    = (float*) (ws + 172457984);   // 52.43 MB  (end ~224.9 MB)

  k_gram<<<BB, 256, 0, stream>>>(x, gram);
  k_conv1pool<<<BB, 256, 0, stream>>>(gram, c1w, c1b, pool1);
  k_conv2mfma<<<BB, 512, 0, stream>>>(pool1, c2w, c2b, proc);
  k_fs<<<2048, 256, 0, stream>>>(x, fW1, fb1, fW2, fb2, fsbuf);
  k_attnmlp<<<2048, 256, 0, stream>>>(x, fsbuf, proc, cW1, cb1, cW2, cb2, out_fw, wx);
  k_enc_mfma<<<64, 448, 0, stream>>>(wx, eWih, eWhh, ebih, ebhh, enc);
  k_attn<<<BB, 256, 0, stream>>>(enc, aW1, ab1, aW2, ab2, bW, bb, h0W, h0b, c0W, c0b,
                                 dWih, dbih, dbhh, out_tw, dh0, dc0, decpre);
  k_dec_mfma<<<64, 448, 0, stream>>>(decpre, dWhh, dh0, dc0, dec);
  k_out<<<2048, 256, 0, stream>>>(dec, oW, ob, out0);
}